// Round 1
// baseline (13865.002 us; speedup 1.0000x reference)
//
#include <hip/hip_runtime.h>
#include <cmath>

// Problem constants (match reference file)
#define B  64
#define S  100
#define H  1024
#define H2 2048
#define H3 3072
#define V  32000
#define LSTEPS 50

// d_out layout (floats): logits [B,L,V] | hT [B,H] | attn [B,L,S]
#define OUT_HT   102400000LL          // B*L*V
#define OUT_ATTN 102465536LL          // + B*H

// workspace layout (float offsets)
#define OFF_UAK 0LL                   // B*S*H        = 6,553,600
#define OFF_QP  6553600LL             // 8*B*H        =   524,288
#define OFF_Q   7077888LL             // B*H          =    65,536
#define OFF_GIP 7143424LL             // 8*B*3H       = 1,572,864
#define OFF_GHP 8716288LL             // 8*B*3H       = 1,572,864
#define OFF_X   10289152LL            // B*3H         =   196,608
#define OFF_E   10485760LL            // B*S          =     6,400
#define OFF_H   10492160LL            // B*H          =    65,536
#define OFF_TOK 10557696LL            // B int32

// ---------------------------------------------------------------------------
// init: h = encoder_hidden[0], tok = 0
__global__ void k_init(const float* __restrict__ eh, float* __restrict__ h,
                       int* __restrict__ tok) {
    int i = blockIdx.x * 256 + threadIdx.x;
    if (i < B * H) h[i] = eh[i];
    if (i < B) tok[i] = 0;
}

// ---------------------------------------------------------------------------
// Fat GEMM: C[m,n] = sum_k A[m,k]*W[n,k] + bias[n]
// A:[M,K] row-major, W:[N,K] row-major. BM=128, BN=64, BK=16, 256 thr, 8x4/thr
// Used for UaK: M=6400 (b*s), N=1024, K=2048.
__global__ __launch_bounds__(256) void k_gemm_fat(
    const float* __restrict__ A, const float* __restrict__ W,
    const float* __restrict__ bias, float* __restrict__ C, int K, int N)
{
    __shared__ __align__(16) float As[16][132];   // [k][m], pad 4
    __shared__ __align__(16) float Ws[16][68];    // [k][n], pad 4
    const int tid = threadIdx.x;
    const int tn  = tid & 15;          // n = tn*4   (0..63)
    const int tm  = tid >> 4;          // m = tm*8   (0..127)
    const long m0 = (long)blockIdx.y * 128;
    const int  n0 = blockIdx.x * 64;

    float acc[8][4];
#pragma unroll
    for (int i = 0; i < 8; i++)
#pragma unroll
        for (int j = 0; j < 4; j++) acc[i][j] = 0.f;

    for (int k0 = 0; k0 < K; k0 += 16) {
#pragma unroll
        for (int i = 0; i < 2; i++) {              // A tile: 128x16
            int f = tid + 256 * i;
            int m = f >> 2, kq = f & 3;
            float4 av = *(const float4*)(A + (m0 + m) * (long)K + k0 + kq * 4);
            As[kq*4+0][m] = av.x; As[kq*4+1][m] = av.y;
            As[kq*4+2][m] = av.z; As[kq*4+3][m] = av.w;
        }
        {                                          // W tile: 64x16
            int n = tid >> 2, kq = tid & 3;
            float4 wv = *(const float4*)(W + (long)(n0 + n) * K + k0 + kq * 4);
            Ws[kq*4+0][n] = wv.x; Ws[kq*4+1][n] = wv.y;
            Ws[kq*4+2][n] = wv.z; Ws[kq*4+3][n] = wv.w;
        }
        __syncthreads();
#pragma unroll
        for (int kk = 0; kk < 16; kk++) {
            float4 a0 = *(const float4*)&As[kk][tm * 8];
            float4 a1 = *(const float4*)&As[kk][tm * 8 + 4];
            float4 wf = *(const float4*)&Ws[kk][tn * 4];
            float a[8] = {a0.x,a0.y,a0.z,a0.w,a1.x,a1.y,a1.z,a1.w};
            float w[4] = {wf.x,wf.y,wf.z,wf.w};
#pragma unroll
            for (int i = 0; i < 8; i++)
#pragma unroll
                for (int j = 0; j < 4; j++)
                    acc[i][j] = fmaf(a[i], w[j], acc[i][j]);
        }
        __syncthreads();
    }
#pragma unroll
    for (int i = 0; i < 8; i++) {
        long m = m0 + tm * 8 + i;
#pragma unroll
        for (int j = 0; j < 4; j++) {
            int n = n0 + tn * 4 + j;
            C[m * N + n] = acc[i][j] + bias[n];
        }
    }
}

// ---------------------------------------------------------------------------
// Skinny GEMM (M=64): C[m,n] = sum_{k in this split's chunk} A[m,k]*W[n,k]
// BN=128, BK=16, 256 thr, 8x4/thr. nsplit>1: write partials [c][64][N];
// nsplit==1: write C[m*ldc+n] + bias[n].
__global__ __launch_bounds__(256) void k_gemm_skinny(
    const float* __restrict__ A, const float* __restrict__ W,
    const float* __restrict__ bias, float* __restrict__ C,
    int K, int N, long ldc, int nsplit)
{
    __shared__ __align__(16) float As[16][68];    // [k][m], pad 4
    __shared__ __align__(16) float Ws[16][132];   // [k][n], pad 4
    const int tid = threadIdx.x;
    const int tn  = tid & 31;          // n = tn*4 (0..127)
    const int tm  = tid >> 5;          // m = tm*8 (0..63)
    const int n0  = blockIdx.x * 128;
    const int Kc  = K / nsplit;
    const int kbeg = blockIdx.y * Kc;

    float acc[8][4];
#pragma unroll
    for (int i = 0; i < 8; i++)
#pragma unroll
        for (int j = 0; j < 4; j++) acc[i][j] = 0.f;

    for (int k0 = kbeg; k0 < kbeg + Kc; k0 += 16) {
        {                                          // A tile: 64x16
            int m = tid >> 2, kq = tid & 3;
            float4 av = *(const float4*)(A + (long)m * K + k0 + kq * 4);
            As[kq*4+0][m] = av.x; As[kq*4+1][m] = av.y;
            As[kq*4+2][m] = av.z; As[kq*4+3][m] = av.w;
        }
#pragma unroll
        for (int i = 0; i < 2; i++) {              // W tile: 128x16
            int f = tid + 256 * i;
            int n = f >> 2, kq = f & 3;
            float4 wv = *(const float4*)(W + (long)(n0 + n) * K + k0 + kq * 4);
            Ws[kq*4+0][n] = wv.x; Ws[kq*4+1][n] = wv.y;
            Ws[kq*4+2][n] = wv.z; Ws[kq*4+3][n] = wv.w;
        }
        __syncthreads();
#pragma unroll
        for (int kk = 0; kk < 16; kk++) {
            float4 a0 = *(const float4*)&As[kk][tm * 8];
            float4 a1 = *(const float4*)&As[kk][tm * 8 + 4];
            float4 wf = *(const float4*)&Ws[kk][tn * 4];
            float a[8] = {a0.x,a0.y,a0.z,a0.w,a1.x,a1.y,a1.z,a1.w};
            float w[4] = {wf.x,wf.y,wf.z,wf.w};
#pragma unroll
            for (int i = 0; i < 8; i++)
#pragma unroll
                for (int j = 0; j < 4; j++)
                    acc[i][j] = fmaf(a[i], w[j], acc[i][j]);
        }
        __syncthreads();
    }
    if (nsplit > 1) {
        float* Cp = C + (long)blockIdx.y * 64 * N;
#pragma unroll
        for (int i = 0; i < 8; i++)
#pragma unroll
            for (int j = 0; j < 4; j++)
                Cp[(long)(tm * 8 + i) * N + n0 + tn * 4 + j] = acc[i][j];
    } else {
#pragma unroll
        for (int i = 0; i < 8; i++)
#pragma unroll
            for (int j = 0; j < 4; j++) {
                int n = n0 + tn * 4 + j;
                C[(long)(tm * 8 + i) * ldc + n] = acc[i][j] + bias[n];
            }
    }
}

// ---------------------------------------------------------------------------
// q reduce: q[b,i] = sum_c qp[c][b,i] + Wa_b[i]      (65536 threads)
__global__ void k_qreduce(const float* __restrict__ qp,
                          const float* __restrict__ Wa_b, float* __restrict__ q) {
    int i = blockIdx.x * 256 + threadIdx.x;
    float s = Wa_b[i & (H - 1)];
#pragma unroll
    for (int c = 0; c < 8; c++) s += qp[(long)c * (B * H) + i];
    q[i] = s;
}

// ---------------------------------------------------------------------------
// score: e[b,s] = sum_h Va[h]*tanh(q[b,h] + UaK[b,s,h]) + Va_b. wave per (b,s).
__global__ __launch_bounds__(256) void k_score(
    const float* __restrict__ UaK, const float* __restrict__ q,
    const float* __restrict__ Va, const float* __restrict__ Va_b,
    float* __restrict__ e)
{
    int wid  = blockIdx.x * 4 + (threadIdx.x >> 6);   // 0..6399 == b*S+s
    int lane = threadIdx.x & 63;
    int b = wid / S;
    const float* u  = UaK + (long)wid * H;
    const float* qb = q + (long)b * H;
    float acc = 0.f;
#pragma unroll
    for (int i = 0; i < 4; i++) {
        int idx = i * 256 + lane * 4;
        float4 uv = *(const float4*)(u + idx);
        float4 qv = *(const float4*)(qb + idx);
        float4 vv = *(const float4*)(Va + idx);
        acc += vv.x * tanhf(qv.x + uv.x);
        acc += vv.y * tanhf(qv.y + uv.y);
        acc += vv.z * tanhf(qv.z + uv.z);
        acc += vv.w * tanhf(qv.w + uv.w);
    }
#pragma unroll
    for (int m = 32; m > 0; m >>= 1) acc += __shfl_xor(acc, m, 64);
    if (lane == 0) e[wid] = acc + Va_b[0];
}

// ---------------------------------------------------------------------------
// softmax over S, write attn to d_out, ctx = w @ enc[b], x = [emb[tok], ctx]
__global__ __launch_bounds__(256) void k_softmax_ctx(
    const float* __restrict__ e, const float* __restrict__ enc,
    const float* __restrict__ emb, const int* __restrict__ tok,
    float* __restrict__ x, float* __restrict__ out_attn, int t)
{
    __shared__ float sw[128];
    __shared__ float red[256];
    int b = blockIdx.x, tid = threadIdx.x;
    float v = (tid < S) ? e[b * S + tid] : -1e30f;
    red[tid] = v; __syncthreads();
    for (int s2 = 128; s2 > 0; s2 >>= 1) {
        if (tid < s2) red[tid] = fmaxf(red[tid], red[tid + s2]);
        __syncthreads();
    }
    float mx = red[0]; __syncthreads();
    float p = (tid < S) ? expf(v - mx) : 0.f;
    red[tid] = p; __syncthreads();
    for (int s2 = 128; s2 > 0; s2 >>= 1) {
        if (tid < s2) red[tid] += red[tid + s2];
        __syncthreads();
    }
    float inv = 1.f / red[0];
    if (tid < S) {
        float wv = p * inv;
        sw[tid] = wv;
        out_attn[((long)b * LSTEPS + t) * S + tid] = wv;
    }
    __syncthreads();

    const float* encb = enc + (long)b * S * H2;
    float* xb = x + (long)b * H3;
    float a[8];
#pragma unroll
    for (int j = 0; j < 8; j++) a[j] = 0.f;
    for (int s = 0; s < S; s++) {
        float wv = sw[s];
#pragma unroll
        for (int j = 0; j < 8; j++)
            a[j] = fmaf(wv, encb[(long)s * H2 + tid + j * 256], a[j]);
    }
#pragma unroll
    for (int j = 0; j < 8; j++) xb[H + tid + j * 256] = a[j];

    const float* er = emb + (long)tok[b] * H;
    for (int d = tid; d < H; d += 256) xb[d] = er[d];
}

// ---------------------------------------------------------------------------
// GRU combine: reduce split-K partials of gi/gh, apply gates, update h, emit hT
__global__ void k_gru(const float* __restrict__ gip, const float* __restrict__ ghp,
                      const float* __restrict__ b_ih, const float* __restrict__ b_hh,
                      float* __restrict__ h, float* __restrict__ out_ht)
{
    int idx = blockIdx.x * 256 + threadIdx.x;   // < B*H
    int b = idx >> 10, i = idx & (H - 1);
    float ir = b_ih[i], iz = b_ih[H + i], in_ = b_ih[H2 + i];
    float hr = b_hh[i], hz = b_hh[H + i], hn = b_hh[H2 + i];
#pragma unroll
    for (int c = 0; c < 8; c++) {
        const float* gp = gip + ((long)c * B + b) * H3;
        ir += gp[i]; iz += gp[H + i]; in_ += gp[H2 + i];
        const float* hp = ghp + ((long)c * B + b) * H3;
        hr += hp[i]; hz += hp[H + i]; hn += hp[H2 + i];
    }
    float r = 1.f / (1.f + expf(-(ir + hr)));
    float z = 1.f / (1.f + expf(-(iz + hz)));
    float n = tanhf(in_ + r * hn);
    float hv = h[idx];
    float hnew = (1.f - z) * n + z * hv;
    h[idx] = hnew;
    out_ht[idx] = hnew;
}

// ---------------------------------------------------------------------------
// argmax over V with first-index tie-break (matches jnp.argmax)
__global__ __launch_bounds__(256) void k_argmax(const float* __restrict__ logits,
                                                int* __restrict__ tok)
{
    __shared__ float bv[256];
    __shared__ int   bi[256];
    int b = blockIdx.x, tid = threadIdx.x;
    const float* lb = logits + (long)b * LSTEPS * V;
    float best = -1e38f; int besti = 0;
    for (int v = tid; v < V; v += 256) {
        float xv = lb[v];
        if (xv > best) { best = xv; besti = v; }
    }
    bv[tid] = best; bi[tid] = besti; __syncthreads();
    for (int s2 = 128; s2 > 0; s2 >>= 1) {
        if (tid < s2) {
            float ov = bv[tid + s2]; int oi = bi[tid + s2];
            if (ov > bv[tid] || (ov == bv[tid] && oi < bi[tid])) {
                bv[tid] = ov; bi[tid] = oi;
            }
        }
        __syncthreads();
    }
    if (tid == 0) tok[b] = bi[0];
}

// ---------------------------------------------------------------------------
extern "C" void kernel_launch(void* const* d_in, const int* in_sizes, int n_in,
                              void* d_out_, int out_size, void* d_ws, size_t ws_size,
                              hipStream_t stream)
{
    const float* enc   = (const float*)d_in[0];
    const float* eh    = (const float*)d_in[1];
    // d_in[2] = max_len (50, hardcoded as LSTEPS)
    const float* emb   = (const float*)d_in[3];
    const float* Wa_w  = (const float*)d_in[4];
    const float* Wa_b  = (const float*)d_in[5];
    const float* Ua_w  = (const float*)d_in[6];
    const float* Ua_b  = (const float*)d_in[7];
    const float* Va_w  = (const float*)d_in[8];
    const float* Va_b  = (const float*)d_in[9];
    const float* W_ih  = (const float*)d_in[10];
    const float* W_hh  = (const float*)d_in[11];
    const float* b_ih  = (const float*)d_in[12];
    const float* b_hh  = (const float*)d_in[13];
    const float* W_out = (const float*)d_in[14];
    const float* b_out = (const float*)d_in[15];
    float* out = (float*)d_out_;
    float* ws  = (float*)d_ws;

    float* UaK = ws + OFF_UAK;
    float* qp  = ws + OFF_QP;
    float* q   = ws + OFF_Q;
    float* gip = ws + OFF_GIP;
    float* ghp = ws + OFF_GHP;
    float* x   = ws + OFF_X;
    float* e   = ws + OFF_E;
    float* h   = ws + OFF_H;
    int*   tok = (int*)(ws + OFF_TOK);

    k_init<<<dim3(256), dim3(256), 0, stream>>>(eh, h, tok);
    // UaK = enc @ Ua_w^T + Ua_b : M=6400, N=1024, K=2048
    k_gemm_fat<<<dim3(H / 64, (B * S) / 128), dim3(256), 0, stream>>>(
        enc, Ua_w, Ua_b, UaK, H2, H);

    for (int t = 0; t < LSTEPS; t++) {
        // q = h @ Wa_w^T (+Wa_b in reduce): N=1024, K=1024, splitK=8
        k_gemm_skinny<<<dim3(H / 128, 8), dim3(256), 0, stream>>>(
            h, Wa_w, nullptr, qp, H, H, (long)H, 8);
        k_qreduce<<<dim3(B * H / 256), dim3(256), 0, stream>>>(qp, Wa_b, q);
        k_score<<<dim3(B * S / 4), dim3(256), 0, stream>>>(UaK, q, Va_w, Va_b, e);
        k_softmax_ctx<<<dim3(B), dim3(256), 0, stream>>>(
            e, enc, emb, tok, x, out + OUT_ATTN, t);
        // gi = x @ W_ih^T : N=3072, K=3072, splitK=8
        k_gemm_skinny<<<dim3(H3 / 128, 8), dim3(256), 0, stream>>>(
            x, W_ih, nullptr, gip, H3, H3, (long)H3, 8);
        // gh = h @ W_hh^T : N=3072, K=1024, splitK=8
        k_gemm_skinny<<<dim3(H3 / 128, 8), dim3(256), 0, stream>>>(
            h, W_hh, nullptr, ghp, H, H3, (long)H3, 8);
        k_gru<<<dim3(B * H / 256), dim3(256), 0, stream>>>(
            gip, ghp, b_ih, b_hh, h, out + OUT_HT);
        // logits = h_new @ W_out^T + b_out -> d_out[b][t][:] : N=32000, K=1024
        k_gemm_skinny<<<dim3(V / 128, 1), dim3(256), 0, stream>>>(
            h, W_out, b_out, out + (long)t * V, H, V, (long)LSTEPS * V, 1);
        k_argmax<<<dim3(B), dim3(256), 0, stream>>>(out + (long)t * V, tok);
    }
}